// Round 10
// baseline (184.819 us; speedup 1.0000x reference)
//
#include <hip/hip_runtime.h>
#include <hip/hip_bf16.h>

typedef __attribute__((ext_vector_type(8))) short short8;
typedef __attribute__((ext_vector_type(4))) float f32x4;
typedef __attribute__((ext_vector_type(16))) float f32x16;
typedef __attribute__((ext_vector_type(8))) int int8v;

#define D   512
#define NQ  2048
#define NS  4096
#define NB  8
#define BM  128
#define BN  128
#define BK  32

typedef const __attribute__((address_space(1))) unsigned int gas_uint;
typedef __attribute__((address_space(3))) unsigned int las_uint;

// s_waitcnt immediates (gfx9 encoding): expcnt=7, lgkmcnt=15 (no-wait) unless noted
#define WAIT_VM4   0x0F74   // vmcnt(4)
#define WAIT_VM0   0x0F70   // vmcnt(0)
#define WAIT_LGKM0 0xC07F   // lgkmcnt(0), vmcnt no-wait

// round-to-nearest-even fp32 -> bf16 bits (fallback path)
__device__ __forceinline__ short f2bf(float f) {
  unsigned u = __builtin_bit_cast(unsigned, f);
  unsigned r = u + 0x7fffu + ((u >> 16) & 1u);
  return (short)(r >> 16);
}

__device__ __forceinline__ short8 pack8(float4 a, float4 b, float r) {
  short8 o;
  o[0] = f2bf(a.x * r); o[1] = f2bf(a.y * r); o[2] = f2bf(a.z * r); o[3] = f2bf(a.w * r);
  o[4] = f2bf(b.x * r); o[5] = f2bf(b.y * r); o[6] = f2bf(b.z * r); o[7] = f2bf(b.w * r);
  return o;
}

// ============================ FAST PATH (fp8 MX) ============================
__global__ void normcvt8_kernel(const float* __restrict__ q, const float* __restrict__ s,
                                unsigned char* __restrict__ qn, unsigned char* __restrict__ sn,
                                unsigned* __restrict__ maxenc) {
  if (blockIdx.x < 64) maxenc[(blockIdx.x << 8) | threadIdx.x] = 0;
  int wave = blockIdx.x * 4 + (threadIdx.x >> 6);
  int lane = threadIdx.x & 63;
  const int NQR = NB * NQ;
  const float4* src; unsigned char* dst;
  if (wave < NQR) { src = (const float4*)(q + (size_t)wave * D); dst = qn + (size_t)wave * D; }
  else {
    size_t w = wave - NQR;
    src = (const float4*)(s + w * D); dst = sn + w * D;
  }
  float4 a = src[lane * 2];
  float4 b = src[lane * 2 + 1];
  float ss = a.x*a.x + a.y*a.y + a.z*a.z + a.w*a.w
           + b.x*b.x + b.y*b.y + b.z*b.z + b.w*b.w;
  #pragma unroll
  for (int m = 32; m >= 1; m >>= 1) ss += __shfl_xor(ss, m, 64);
  float r = 1.0f / fmaxf(sqrtf(ss), 1e-12f);
  int w0 = __builtin_amdgcn_cvt_pk_fp8_f32(a.x * r, a.y * r, 0, false);
  w0     = __builtin_amdgcn_cvt_pk_fp8_f32(a.z * r, a.w * r, w0, true);
  int w1 = __builtin_amdgcn_cvt_pk_fp8_f32(b.x * r, b.y * r, 0, false);
  w1     = __builtin_amdgcn_cvt_pk_fp8_f32(b.z * r, b.w * r, w1, true);
  *(int2*)(dst + lane * 8) = make_int2(w0, w1);
}

// ---------------------------------------------------------------------------
// cosmax10: round-9 pipeline (raw s_barrier + vmcnt(4), 3 rotating 16 KB LDS
// buffers, A persistent in registers, rolled S-tile loop) with the grid sized
// to EXACTLY 3 blocks/CU = 768 blocks (zero quantization tail): S's 32
// column-tiles split 11/11/10 across blockIdx.x. Round 9's 1024-block grid
// left half the runtime at 1 block/CU (avg occupancy 19.5% vs 37.5% cap).
// ---------------------------------------------------------------------------
__global__ __launch_bounds__(256) void cosmax10_kernel(
    const unsigned char* __restrict__ Qn, const unsigned char* __restrict__ Sn,
    unsigned int* __restrict__ maxenc)
{
  __shared__ __align__(16) unsigned char sbuf[49152];   // 3 x 16 KB stage buffers
  __shared__ float maxbuf[64][2];

  const int b   = blockIdx.z;
  const int mt  = blockIdx.y;          // 0..31 : 64-row q tile
  const int nsp = blockIdx.x;          // 0..2  : S-tile group (11/11/10 tiles)
  const int t0    = nsp * 11;          // first 128-row S tile
  const int ntile = (nsp < 2) ? 11 : 10;
  const int tid  = threadIdx.x;
  const int wave = tid >> 6;           // 0..3
  const int lane = tid & 63;
  const int l31 = lane & 31, kc = lane >> 5;
  const int mstrip = wave & 1, nhalf = wave >> 1;

  // ---------------- Q prologue: stage 64x512B into sbuf[16384..49152) -------
  {
    const unsigned char* Qbase = Qn + ((size_t)b * NQ + (size_t)mt * 64) * D;
    const int baserow = wave * 2 + (lane >> 5);          // 0..7
    #pragma unroll
    for (int p = 0; p < 8; ++p) {
      int row = p * 8 + baserow;                          // 0..63
      int g   = (lane & 31) ^ (row & 31);                 // 16B-chunk XOR swizzle
      __builtin_amdgcn_global_load_lds(
          (gas_uint*)(Qbase + (size_t)row * D + g * 16),
          (las_uint*)(sbuf + 16384 + p * 4096 + wave * 1024), 16, 0, 0);
    }
  }
  __syncthreads();                                        // drains Q DMA

  // ---------------- B staging setup (per-lane global base) ------------------
  const int srow8 = lane >> 3;                            // 0..7
  const int sch   = (lane & 7) ^ srow8;
  const unsigned char* gS = Sn +
      ((size_t)b * NS + (size_t)t0 * 128 + wave * 32 + srow8) * D + sch * 16;

  auto issue = [&](size_t goff, int ldsoff) {
    #pragma unroll
    for (int t = 0; t < 4; ++t)
      __builtin_amdgcn_global_load_lds((gas_uint*)(gS + goff + (size_t)t * 4096),
          (las_uint*)(sbuf + ldsoff + wave * 4096 + t * 1024), 16, 0, 0);
  };

  // stage (0,0) -> buf0 [0,16384): does not touch Q region; overlaps a-frag reads
  issue(0, 0);

  // ---------------- A fragments: registers, full K ---------------------------
  const int arow = mstrip * 32 + l31;
  int8v a[8];
  #pragma unroll
  for (int kk = 0; kk < 8; ++kk) {
    int c0 = (4 * kk + 2 * kc) ^ l31;
    ((int4*)&a[kk])[0] = *(const int4*)&sbuf[16384 + arow * 512 + c0 * 16];
    ((int4*)&a[kk])[1] = *(const int4*)&sbuf[16384 + arow * 512 + (c0 ^ 1) * 16];
  }
  // all waves must finish reading Q before stage (0,1) DMA overwrites it
  __builtin_amdgcn_s_waitcnt(WAIT_LGKM0);
  asm volatile("" ::: "memory");
  __builtin_amdgcn_s_barrier();
  asm volatile("" ::: "memory");
  issue(128, 16384);                                      // stage (0,1) -> buf1

  // ---------------- accumulators --------------------------------------------
  const int brow0 = (nhalf * 64 + l31) * 128;
  const int brow1 = brow0 + 4096;                         // +32 s-rows
  const int cxor  = ((kc * 2) ^ (l31 & 7)) * 16;

  f32x16 acc0, acc1;
  float rmax[16];
  #pragma unroll
  for (int r = 0; r < 16; ++r) rmax[r] = -2.0f;

  int rd = 0, wr = 32768;

  auto computeK = [&](int kt, int rdo) {
    const unsigned char* Bb = sbuf + rdo;
    #pragma unroll
    for (int ss = 0; ss < 2; ++ss) {
      const int cb = cxor ^ (ss * 64);
      int8v b0, b1;
      ((int4*)&b0)[0] = *(const int4*)&Bb[brow0 + cb];
      ((int4*)&b0)[1] = *(const int4*)&Bb[brow0 + (cb ^ 16)];
      ((int4*)&b1)[0] = *(const int4*)&Bb[brow1 + cb];
      ((int4*)&b1)[1] = *(const int4*)&Bb[brow1 + (cb ^ 16)];
      acc0 = __builtin_amdgcn_mfma_scale_f32_32x32x64_f8f6f4(
          a[kt * 2 + ss], b0, acc0, 0, 0, 0, 0x7f7f7f7f, 0, 0x7f7f7f7f);
      acc1 = __builtin_amdgcn_mfma_scale_f32_32x32x64_f8f6f4(
          a[kt * 2 + ss], b1, acc1, 0, 0, 0, 0x7f7f7f7f, 0, 0x7f7f7f7f);
    }
  };

  #define ROT(x) x = (x == 32768) ? 0 : x + 16384

  #pragma clang loop unroll(disable)
  for (int nt2 = 0; nt2 < ntile; ++nt2) {
    const size_t ntb = (size_t)nt2 << 16;                 // 128 rows * 512 B
    const bool more = (nt2 < ntile - 1);

    // ---- kt = 0
    __builtin_amdgcn_s_waitcnt(WAIT_VM4);
    asm volatile("" ::: "memory");
    __builtin_amdgcn_s_barrier();
    asm volatile("" ::: "memory");
    issue(ntb + 256, wr); ROT(wr);
    #pragma unroll
    for (int r = 0; r < 16; ++r) { acc0[r] = 0.f; acc1[r] = 0.f; }
    computeK(0, rd); ROT(rd);

    // ---- kt = 1
    __builtin_amdgcn_s_waitcnt(WAIT_VM4);
    asm volatile("" ::: "memory");
    __builtin_amdgcn_s_barrier();
    asm volatile("" ::: "memory");
    issue(ntb + 384, wr); ROT(wr);
    computeK(1, rd); ROT(rd);

    // ---- kt = 2
    __builtin_amdgcn_s_waitcnt(WAIT_VM4);
    asm volatile("" ::: "memory");
    __builtin_amdgcn_s_barrier();
    asm volatile("" ::: "memory");
    if (more) { issue(ntb + 65536, wr); ROT(wr); }
    computeK(2, rd); ROT(rd);

    // ---- kt = 3
    if (more) __builtin_amdgcn_s_waitcnt(WAIT_VM4);
    else      __builtin_amdgcn_s_waitcnt(WAIT_VM0);
    asm volatile("" ::: "memory");
    __builtin_amdgcn_s_barrier();
    asm volatile("" ::: "memory");
    if (more) { issue(ntb + 65536 + 128, wr); ROT(wr); }
    computeK(3, rd); ROT(rd);

    #pragma unroll
    for (int r = 0; r < 16; ++r)
      rmax[r] = fmaxf(rmax[r], fmaxf(acc0[r], acc1[r]));
  }
  #undef ROT

  // ---------------- epilogue -------------------------------------------------
  // 32x32 C/D: col = lane&31, row = (reg&3) + 8*(reg>>2) + 4*(lane>>5)
  #pragma unroll
  for (int r = 0; r < 16; ++r) {
    float v = rmax[r];
    v = fmaxf(v, __shfl_xor(v, 1, 64));
    v = fmaxf(v, __shfl_xor(v, 2, 64));
    v = fmaxf(v, __shfl_xor(v, 4, 64));
    v = fmaxf(v, __shfl_xor(v, 8, 64));
    v = fmaxf(v, __shfl_xor(v, 16, 64));
    if (l31 == 0)
      maxbuf[mstrip * 32 + (r & 3) + 8 * (r >> 2) + 4 * kc][nhalf] = v;
  }
  __syncthreads();

  if (tid < 64) {
    float v = fmaxf(maxbuf[tid][0], maxbuf[tid][1]);
    unsigned e = __builtin_bit_cast(unsigned, v);
    e = ((int)e >= 0) ? (e | 0x80000000u) : ~e;           // monotone float->uint
    atomicMax(&maxenc[(size_t)b * NQ + (size_t)mt * 64 + tid], e);
  }
}

__global__ void finalize_kernel(const unsigned* __restrict__ maxenc,
                                float* __restrict__ out) {
  int b = blockIdx.x;
  int tid = threadIdx.x;
  float sum = 0.f;
  for (int i = tid; i < NQ; i += 256) {
    unsigned e = maxenc[(size_t)b * NQ + i];
    unsigned u = (e & 0x80000000u) ? (e & 0x7fffffffu) : ~e;
    float v = __builtin_bit_cast(float, u);
    sum += 1.0f - v;
  }
  #pragma unroll
  for (int m = 32; m >= 1; m >>= 1) sum += __shfl_xor(sum, m, 64);
  __shared__ float part[4];
  if ((tid & 63) == 0) part[tid >> 6] = sum;
  __syncthreads();
  if (tid == 0) out[b] = (part[0] + part[1] + part[2] + part[3]) * (1.0f / (float)NQ);
}

// ====================== FALLBACK PATH (round-1, proven, tiny ws) ============
__global__ void norms_kernel(const float* __restrict__ q, const float* __restrict__ s,
                             float* __restrict__ rq, float* __restrict__ rs) {
  int wave = blockIdx.x * 4 + (threadIdx.x >> 6);
  int lane = threadIdx.x & 63;
  const int NQR = NB * NQ, NSR = NB * NS;
  if (wave >= NQR + NSR) return;
  const float4* r4; float* outp;
  if (wave < NQR) { r4 = (const float4*)(q + (size_t)wave * D); outp = rq + wave; }
  else           { r4 = (const float4*)(s + (size_t)(wave - NQR) * D); outp = rs + (wave - NQR); }
  float4 a = r4[lane];
  float4 b = r4[lane + 64];
  float ss = a.x*a.x + a.y*a.y + a.z*a.z + a.w*a.w
           + b.x*b.x + b.y*b.y + b.z*b.z + b.w*b.w;
  #pragma unroll
  for (int m = 32; m >= 1; m >>= 1) ss += __shfl_xor(ss, m, 64);
  if (lane == 0) *outp = 1.0f / fmaxf(sqrtf(ss), 1e-12f);
}

__global__ __launch_bounds__(256, 3) void cosmax_kernel(
    const float* __restrict__ Q, const float* __restrict__ S,
    const float* __restrict__ rq, const float* __restrict__ rs,
    unsigned int* __restrict__ maxenc)
{
  __shared__ short As[BM * BK];
  __shared__ short Bs[BN * BK];
  __shared__ float maxbuf[BM][2];

  const int b  = blockIdx.z, mt = blockIdx.y, nt = blockIdx.x;
  const float* Qb  = Q + ((size_t)b * NQ + mt * BM) * D;
  const float* Sb  = S + ((size_t)b * NS + nt * BN) * D;
  const float* rqb = rq + (size_t)b * NQ + mt * BM;
  const float* rsb = rs + (size_t)b * NS + nt * BN;

  const int tid  = threadIdx.x;
  const int srow = tid >> 2;
  const int kseg = (tid & 3) * 8;
  const float rq0 = rqb[srow], rq1 = rqb[srow + 64];
  const float rs0 = rsb[srow], rs1 = rsb[srow + 64];
  const int wave = tid >> 6, lane = tid & 63;
  const int wm = (wave & 1) * 64, wn = (wave >> 1) * 64;
  const int lm = lane & 15, lk = (lane >> 4) * 8;

  f32x4 acc[4][4];
  #pragma unroll
  for (int i = 0; i < 4; ++i)
    #pragma unroll
    for (int j = 0; j < 4; ++j) acc[i][j] = (f32x4){0.f, 0.f, 0.f, 0.f};

  const float* qrow0 = Qb + (size_t)srow * D + kseg;
  const float* qrow1 = qrow0 + (size_t)64 * D;
  const float* srow0 = Sb + (size_t)srow * D + kseg;
  const float* srow1 = srow0 + (size_t)64 * D;

  float4 qa, qb2, qc, qd, sa, sb2, sc, sd;
  #define LOADK(k0)                                                    \
    qa  = *(const float4*)(qrow0 + (k0));  qb2 = *(const float4*)(qrow0 + (k0) + 4); \
    qc  = *(const float4*)(qrow1 + (k0));  qd  = *(const float4*)(qrow1 + (k0) + 4); \
    sa  = *(const float4*)(srow0 + (k0));  sb2 = *(const float4*)(srow0 + (k0) + 4); \
    sc  = *(const float4*)(srow1 + (k0));  sd  = *(const float4*)(srow1 + (k0) + 4);
  LOADK(0);
  #pragma unroll 4
  for (int kt = 0; kt < D / BK; ++kt) {
    *(short8*)&As[srow        * BK + kseg] = pack8(qa, qb2, rq0);
    *(short8*)&As[(srow + 64) * BK + kseg] = pack8(qc, qd,  rq1);
    *(short8*)&Bs[srow        * BK + kseg] = pack8(sa, sb2, rs0);
    *(short8*)&Bs[(srow + 64) * BK + kseg] = pack8(sc, sd,  rs1);
    __syncthreads();
    if (kt < D / BK - 1) { LOADK((kt + 1) * BK); }
    short8 af[4], bf[4];
    #pragma unroll
    for (int i = 0; i < 4; ++i) af[i] = *(short8*)&As[(wm + i * 16 + lm) * BK + lk];
    #pragma unroll
    for (int j = 0; j < 4; ++j) bf[j] = *(short8*)&Bs[(wn + j * 16 + lm) * BK + lk];
    #pragma unroll
    for (int i = 0; i < 4; ++i)
      #pragma unroll
      for (int j = 0; j < 4; ++j)
        acc[i][j] = __builtin_amdgcn_mfma_f32_16x16x32_bf16(af[i], bf[j], acc[i][j], 0, 0, 0);
    __syncthreads();
  }
  #undef LOADK

  #pragma unroll
  for (int i = 0; i < 4; ++i) {
    #pragma unroll
    for (int r = 0; r < 4; ++r) {
      float v = fmaxf(fmaxf(acc[i][0][r], acc[i][1][r]),
                      fmaxf(acc[i][2][r], acc[i][3][r]));
      v = fmaxf(v, __shfl_xor(v, 1, 64));
      v = fmaxf(v, __shfl_xor(v, 2, 64));
      v = fmaxf(v, __shfl_xor(v, 4, 64));
      v = fmaxf(v, __shfl_xor(v, 8, 64));
      if ((lane & 15) == 0) {
        int row = wm + i * 16 + (lane >> 4) * 4 + r;
        maxbuf[row][wave >> 1] = v;
      }
    }
  }
  __syncthreads();
  if (tid < BM) {
    float v = fmaxf(maxbuf[tid][0], maxbuf[tid][1]);
    unsigned e = __builtin_bit_cast(unsigned, v);
    e = ((int)e >= 0) ? (e | 0x80000000u) : ~e;
    atomicMax(&maxenc[(size_t)b * NQ + mt * BM + tid], e);
  }
}

// ============================================================================
extern "C" void kernel_launch(void* const* d_in, const int* in_sizes, int n_in,
                              void* d_out, int out_size, void* d_ws, size_t ws_size,
                              hipStream_t stream) {
  const float* q = (const float*)d_in[0];   // [8,2048,512]
  const float* s = (const float*)d_in[1];   // [8,4096,512]
  float* out = (float*)d_out;               // [8]

  unsigned* maxenc = (unsigned*)d_ws;                         // 64 KB
  const size_t QOFF = 65536;
  const size_t SOFF = QOFF + (size_t)NB * NQ * D;             // +8 MiB (fp8)
  const size_t NEED = SOFF + (size_t)NB * NS * D;             // +16 MiB (~25.2 MB total)

  if (ws_size >= NEED) {
    unsigned char* qn = (unsigned char*)d_ws + QOFF;
    unsigned char* sn = (unsigned char*)d_ws + SOFF;
    normcvt8_kernel<<<NB * (NQ + NS) / 4, 256, 0, stream>>>(q, s, qn, sn, maxenc);
    dim3 grid10(3, NQ / 64, NB);            // 3 x 32 x 8 = 768 blocks = 3/CU exact
    cosmax10_kernel<<<grid10, 256, 0, stream>>>(qn, sn, maxenc);
    finalize_kernel<<<NB, 256, 0, stream>>>(maxenc, out);
  } else {
    float* rq = (float*)((char*)d_ws + 65536);
    float* rs = (float*)((char*)d_ws + 131072);
    hipMemsetAsync(maxenc, 0, (size_t)NB * NQ * sizeof(unsigned), stream);
    norms_kernel<<<NB * (NQ + NS) / 4, 256, 0, stream>>>(q, s, rq, rs);
    dim3 grid(NS / BN, NQ / BM, NB);
    cosmax_kernel<<<grid, 256, 0, stream>>>(q, s, rq, rs, maxenc);
    finalize_kernel<<<NB, 256, 0, stream>>>(maxenc, out);
  }
}

// Round 11
// 161.070 us; speedup vs baseline: 1.1474x; 1.1474x over previous
//
#include <hip/hip_runtime.h>
#include <hip/hip_bf16.h>

typedef __attribute__((ext_vector_type(8))) short short8;
typedef __attribute__((ext_vector_type(4))) float f32x4;
typedef __attribute__((ext_vector_type(16))) float f32x16;
typedef __attribute__((ext_vector_type(8))) int int8v;

#define D   512
#define NQ  2048
#define NS  4096
#define NB  8
#define BM  128
#define BN  128
#define BK  32

typedef const __attribute__((address_space(1))) unsigned int gas_uint;
typedef __attribute__((address_space(3))) unsigned int las_uint;

// s_waitcnt immediates (gfx9): vmcnt[3:0]|[15:14], expcnt[6:4]=7, lgkmcnt[11:8]=15 = no-wait
#define WAIT_VM8   0x0F78   // vmcnt(8)
#define WAIT_VM4   0x0F74   // vmcnt(4)
#define WAIT_VM0   0x0F70   // vmcnt(0)
#define WAIT_LGKM0 0xC07F   // lgkmcnt(0), vmcnt no-wait

// round-to-nearest-even fp32 -> bf16 bits (fallback path)
__device__ __forceinline__ short f2bf(float f) {
  unsigned u = __builtin_bit_cast(unsigned, f);
  unsigned r = u + 0x7fffu + ((u >> 16) & 1u);
  return (short)(r >> 16);
}

__device__ __forceinline__ short8 pack8(float4 a, float4 b, float r) {
  short8 o;
  o[0] = f2bf(a.x * r); o[1] = f2bf(a.y * r); o[2] = f2bf(a.z * r); o[3] = f2bf(a.w * r);
  o[4] = f2bf(b.x * r); o[5] = f2bf(b.y * r); o[6] = f2bf(b.z * r); o[7] = f2bf(b.w * r);
  return o;
}

// ============================ FAST PATH (fp8 MX) ============================
__global__ void normcvt8_kernel(const float* __restrict__ q, const float* __restrict__ s,
                                unsigned char* __restrict__ qn, unsigned char* __restrict__ sn,
                                unsigned* __restrict__ maxenc) {
  if (blockIdx.x < 64) maxenc[(blockIdx.x << 8) | threadIdx.x] = 0;
  int wave = blockIdx.x * 4 + (threadIdx.x >> 6);
  int lane = threadIdx.x & 63;
  const int NQR = NB * NQ;
  const float4* src; unsigned char* dst;
  if (wave < NQR) { src = (const float4*)(q + (size_t)wave * D); dst = qn + (size_t)wave * D; }
  else {
    size_t w = wave - NQR;
    src = (const float4*)(s + w * D); dst = sn + w * D;
  }
  float4 a = src[lane * 2];
  float4 b = src[lane * 2 + 1];
  float ss = a.x*a.x + a.y*a.y + a.z*a.z + a.w*a.w
           + b.x*b.x + b.y*b.y + b.z*b.z + b.w*b.w;
  #pragma unroll
  for (int m = 32; m >= 1; m >>= 1) ss += __shfl_xor(ss, m, 64);
  float r = 1.0f / fmaxf(sqrtf(ss), 1e-12f);
  int w0 = __builtin_amdgcn_cvt_pk_fp8_f32(a.x * r, a.y * r, 0, false);
  w0     = __builtin_amdgcn_cvt_pk_fp8_f32(a.z * r, a.w * r, w0, true);
  int w1 = __builtin_amdgcn_cvt_pk_fp8_f32(b.x * r, b.y * r, 0, false);
  w1     = __builtin_amdgcn_cvt_pk_fp8_f32(b.z * r, b.w * r, w1, true);
  *(int2*)(dst + lane * 8) = make_int2(w0, w1);
}

// ---------------------------------------------------------------------------
// cosmax11: round-7 structure (512 blocks, 16 S-tiles/block, A persistent in
// registers, raw s_barrier pipeline) with two changes:
//  1) prefetch distance 3 via 4 static 16 KB buffers (kt_i reads buf_i,
//     issues into buf_(i+3)%4) and s_waitcnt vmcnt(8) — each load gets ~2
//     compute phases in flight (distance-2 couldn't cover L2-miss latency).
//  2) XCD-aware 1-D block decode (b = id&7) so each XCD streams one batch's
//     S (2 MB) + Q (1 MB) < its 4 MB L2 — kills the round-10 L2 thrash.
// ---------------------------------------------------------------------------
__global__ __launch_bounds__(256) void cosmax11_kernel(
    const unsigned char* __restrict__ Qn, const unsigned char* __restrict__ Sn,
    unsigned int* __restrict__ maxenc)
{
  __shared__ __align__(16) unsigned char sbuf[65536];   // 4 x 16 KB stage buffers
  __shared__ float maxbuf[64][2];

  const int id  = blockIdx.x;          // 512 blocks, 1-D
  const int b   = id & 7;              // XCD-aligned batch (round-robin id->XCD)
  const int j   = id >> 3;             // 0..63
  const int mt  = j & 31;              // 64-row q tile
  const int nsp = j >> 5;              // 0..1 : 2048-row s half
  const int tid  = threadIdx.x;
  const int wave = tid >> 6;           // 0..3
  const int lane = tid & 63;
  const int l31 = lane & 31, kc = lane >> 5;
  const int mstrip = wave & 1, nhalf = wave >> 1;

  // ---------------- Q prologue: stage 64x512B into sbuf[16384..49152) -------
  {
    const unsigned char* Qbase = Qn + ((size_t)b * NQ + (size_t)mt * 64) * D;
    const int baserow = wave * 2 + (lane >> 5);          // 0..7
    #pragma unroll
    for (int p = 0; p < 8; ++p) {
      int row = p * 8 + baserow;                          // 0..63
      int g   = (lane & 31) ^ (row & 31);                 // 16B-chunk XOR swizzle
      __builtin_amdgcn_global_load_lds(
          (gas_uint*)(Qbase + (size_t)row * D + g * 16),
          (las_uint*)(sbuf + 16384 + p * 4096 + wave * 1024), 16, 0, 0);
    }
  }
  __syncthreads();                                        // drains Q DMA

  // ---------------- B staging setup (per-lane global base) ------------------
  const int srow8 = lane >> 3;                            // 0..7
  const int sch   = (lane & 7) ^ srow8;
  const unsigned char* gS = Sn +
      ((size_t)b * NS + (size_t)nsp * 2048 + wave * 32 + srow8) * D + sch * 16;

  auto issue = [&](size_t goff, int ldsoff) {
    #pragma unroll
    for (int t = 0; t < 4; ++t)
      __builtin_amdgcn_global_load_lds((gas_uint*)(gS + goff + (size_t)t * 4096),
          (las_uint*)(sbuf + ldsoff + wave * 4096 + t * 1024), 16, 0, 0);
  };

  // stage (tile0,kt0) -> buf0 [0,16384): disjoint from Q region; overlaps A reads
  issue(0, 0);

  // ---------------- A fragments: registers, full K ---------------------------
  const int arow = mstrip * 32 + l31;
  int8v a[8];
  #pragma unroll
  for (int kk = 0; kk < 8; ++kk) {
    int c0 = (4 * kk + 2 * kc) ^ l31;
    ((int4*)&a[kk])[0] = *(const int4*)&sbuf[16384 + arow * 512 + c0 * 16];
    ((int4*)&a[kk])[1] = *(const int4*)&sbuf[16384 + arow * 512 + (c0 ^ 1) * 16];
  }
  // all waves must finish reading Q before stage DMA overwrites buf1/buf2
  __builtin_amdgcn_s_waitcnt(WAIT_LGKM0);
  asm volatile("" ::: "memory");
  __builtin_amdgcn_s_barrier();
  asm volatile("" ::: "memory");
  issue(128, 16384);                                      // (tile0,kt1) -> buf1
  issue(256, 32768);                                      // (tile0,kt2) -> buf2

  // ---------------- accumulators --------------------------------------------
  const int brow0 = (nhalf * 64 + l31) * 128;
  const int brow1 = brow0 + 4096;                         // +32 s-rows
  const int cxor  = ((kc * 2) ^ (l31 & 7)) * 16;

  f32x16 acc0, acc1;
  float rmax[16];
  #pragma unroll
  for (int r = 0; r < 16; ++r) rmax[r] = -2.0f;

  auto computeK = [&](int kt, int rdo) {
    const unsigned char* Bb = sbuf + rdo;
    #pragma unroll
    for (int ss = 0; ss < 2; ++ss) {
      const int cb = cxor ^ (ss * 64);
      int8v b0, b1;
      ((int4*)&b0)[0] = *(const int4*)&Bb[brow0 + cb];
      ((int4*)&b0)[1] = *(const int4*)&Bb[brow0 + (cb ^ 16)];
      ((int4*)&b1)[0] = *(const int4*)&Bb[brow1 + cb];
      ((int4*)&b1)[1] = *(const int4*)&Bb[brow1 + (cb ^ 16)];
      acc0 = __builtin_amdgcn_mfma_scale_f32_32x32x64_f8f6f4(
          a[kt * 2 + ss], b0, acc0, 0, 0, 0, 0x7f7f7f7f, 0, 0x7f7f7f7f);
      acc1 = __builtin_amdgcn_mfma_scale_f32_32x32x64_f8f6f4(
          a[kt * 2 + ss], b1, acc1, 0, 0, 0, 0x7f7f7f7f, 0, 0x7f7f7f7f);
    }
  };

  #pragma clang loop unroll(disable)
  for (int nt2 = 0; nt2 < 16; ++nt2) {
    const size_t ntb = (size_t)nt2 << 16;                 // 128 rows * 512 B
    const bool more = (nt2 < 15);

    // ---- kt = 0 : read buf0, issue (tile,kt3) -> buf3
    __builtin_amdgcn_s_waitcnt(WAIT_VM8);
    asm volatile("" ::: "memory");
    __builtin_amdgcn_s_barrier();
    asm volatile("" ::: "memory");
    issue(ntb + 384, 49152);
    #pragma unroll
    for (int r = 0; r < 16; ++r) { acc0[r] = 0.f; acc1[r] = 0.f; }
    computeK(0, 0);

    // ---- kt = 1 : read buf1, issue (tile+1,kt0) -> buf0
    __builtin_amdgcn_s_waitcnt(WAIT_VM8);
    asm volatile("" ::: "memory");
    __builtin_amdgcn_s_barrier();
    asm volatile("" ::: "memory");
    if (more) issue(ntb + 65536, 0);
    computeK(1, 16384);

    // ---- kt = 2 : read buf2, issue (tile+1,kt1) -> buf1
    if (more) __builtin_amdgcn_s_waitcnt(WAIT_VM8);
    else      __builtin_amdgcn_s_waitcnt(WAIT_VM4);
    asm volatile("" ::: "memory");
    __builtin_amdgcn_s_barrier();
    asm volatile("" ::: "memory");
    if (more) issue(ntb + 65536 + 128, 16384);
    computeK(2, 32768);

    // ---- kt = 3 : read buf3, issue (tile+1,kt2) -> buf2
    if (more) __builtin_amdgcn_s_waitcnt(WAIT_VM8);
    else      __builtin_amdgcn_s_waitcnt(WAIT_VM0);
    asm volatile("" ::: "memory");
    __builtin_amdgcn_s_barrier();
    asm volatile("" ::: "memory");
    if (more) issue(ntb + 65536 + 256, 32768);
    computeK(3, 49152);

    #pragma unroll
    for (int r = 0; r < 16; ++r)
      rmax[r] = fmaxf(rmax[r], fmaxf(acc0[r], acc1[r]));
  }

  // ---------------- epilogue -------------------------------------------------
  // 32x32 C/D: col = lane&31, row = (reg&3) + 8*(reg>>2) + 4*(lane>>5)
  #pragma unroll
  for (int r = 0; r < 16; ++r) {
    float v = rmax[r];
    v = fmaxf(v, __shfl_xor(v, 1, 64));
    v = fmaxf(v, __shfl_xor(v, 2, 64));
    v = fmaxf(v, __shfl_xor(v, 4, 64));
    v = fmaxf(v, __shfl_xor(v, 8, 64));
    v = fmaxf(v, __shfl_xor(v, 16, 64));
    if (l31 == 0)
      maxbuf[mstrip * 32 + (r & 3) + 8 * (r >> 2) + 4 * kc][nhalf] = v;
  }
  __syncthreads();

  if (tid < 64) {
    float v = fmaxf(maxbuf[tid][0], maxbuf[tid][1]);
    unsigned e = __builtin_bit_cast(unsigned, v);
    e = ((int)e >= 0) ? (e | 0x80000000u) : ~e;           // monotone float->uint
    atomicMax(&maxenc[(size_t)b * NQ + (size_t)mt * 64 + tid], e);
  }
}

__global__ void finalize_kernel(const unsigned* __restrict__ maxenc,
                                float* __restrict__ out) {
  int b = blockIdx.x;
  int tid = threadIdx.x;
  float sum = 0.f;
  for (int i = tid; i < NQ; i += 256) {
    unsigned e = maxenc[(size_t)b * NQ + i];
    unsigned u = (e & 0x80000000u) ? (e & 0x7fffffffu) : ~e;
    float v = __builtin_bit_cast(float, u);
    sum += 1.0f - v;
  }
  #pragma unroll
  for (int m = 32; m >= 1; m >>= 1) sum += __shfl_xor(sum, m, 64);
  __shared__ float part[4];
  if ((tid & 63) == 0) part[tid >> 6] = sum;
  __syncthreads();
  if (tid == 0) out[b] = (part[0] + part[1] + part[2] + part[3]) * (1.0f / (float)NQ);
}

// ====================== FALLBACK PATH (round-1, proven, tiny ws) ============
__global__ void norms_kernel(const float* __restrict__ q, const float* __restrict__ s,
                             float* __restrict__ rq, float* __restrict__ rs) {
  int wave = blockIdx.x * 4 + (threadIdx.x >> 6);
  int lane = threadIdx.x & 63;
  const int NQR = NB * NQ, NSR = NB * NS;
  if (wave >= NQR + NSR) return;
  const float4* r4; float* outp;
  if (wave < NQR) { r4 = (const float4*)(q + (size_t)wave * D); outp = rq + wave; }
  else           { r4 = (const float4*)(s + (size_t)(wave - NQR) * D); outp = rs + (wave - NQR); }
  float4 a = r4[lane];
  float4 b = r4[lane + 64];
  float ss = a.x*a.x + a.y*a.y + a.z*a.z + a.w*a.w
           + b.x*b.x + b.y*b.y + b.z*b.z + b.w*b.w;
  #pragma unroll
  for (int m = 32; m >= 1; m >>= 1) ss += __shfl_xor(ss, m, 64);
  if (lane == 0) *outp = 1.0f / fmaxf(sqrtf(ss), 1e-12f);
}

__global__ __launch_bounds__(256, 3) void cosmax_kernel(
    const float* __restrict__ Q, const float* __restrict__ S,
    const float* __restrict__ rq, const float* __restrict__ rs,
    unsigned int* __restrict__ maxenc)
{
  __shared__ short As[BM * BK];
  __shared__ short Bs[BN * BK];
  __shared__ float maxbuf[BM][2];

  const int b  = blockIdx.z, mt = blockIdx.y, nt = blockIdx.x;
  const float* Qb  = Q + ((size_t)b * NQ + mt * BM) * D;
  const float* Sb  = S + ((size_t)b * NS + nt * BN) * D;
  const float* rqb = rq + (size_t)b * NQ + mt * BM;
  const float* rsb = rs + (size_t)b * NS + nt * BN;

  const int tid  = threadIdx.x;
  const int srow = tid >> 2;
  const int kseg = (tid & 3) * 8;
  const float rq0 = rqb[srow], rq1 = rqb[srow + 64];
  const float rs0 = rsb[srow], rs1 = rsb[srow + 64];
  const int wave = tid >> 6, lane = tid & 63;
  const int wm = (wave & 1) * 64, wn = (wave >> 1) * 64;
  const int lm = lane & 15, lk = (lane >> 4) * 8;

  f32x4 acc[4][4];
  #pragma unroll
  for (int i = 0; i < 4; ++i)
    #pragma unroll
    for (int j = 0; j < 4; ++j) acc[i][j] = (f32x4){0.f, 0.f, 0.f, 0.f};

  const float* qrow0 = Qb + (size_t)srow * D + kseg;
  const float* qrow1 = qrow0 + (size_t)64 * D;
  const float* srow0 = Sb + (size_t)srow * D + kseg;
  const float* srow1 = srow0 + (size_t)64 * D;

  float4 qa, qb2, qc, qd, sa, sb2, sc, sd;
  #define LOADK(k0)                                                    \
    qa  = *(const float4*)(qrow0 + (k0));  qb2 = *(const float4*)(qrow0 + (k0) + 4); \
    qc  = *(const float4*)(qrow1 + (k0));  qd  = *(const float4*)(qrow1 + (k0) + 4); \
    sa  = *(const float4*)(srow0 + (k0));  sb2 = *(const float4*)(srow0 + (k0) + 4); \
    sc  = *(const float4*)(srow1 + (k0));  sd  = *(const float4*)(srow1 + (k0) + 4);
  LOADK(0);
  #pragma unroll 4
  for (int kt = 0; kt < D / BK; ++kt) {
    *(short8*)&As[srow        * BK + kseg] = pack8(qa, qb2, rq0);
    *(short8*)&As[(srow + 64) * BK + kseg] = pack8(qc, qd,  rq1);
    *(short8*)&Bs[srow        * BK + kseg] = pack8(sa, sb2, rs0);
    *(short8*)&Bs[(srow + 64) * BK + kseg] = pack8(sc, sd,  rs1);
    __syncthreads();
    if (kt < D / BK - 1) { LOADK((kt + 1) * BK); }
    short8 af[4], bf[4];
    #pragma unroll
    for (int i = 0; i < 4; ++i) af[i] = *(short8*)&As[(wm + i * 16 + lm) * BK + lk];
    #pragma unroll
    for (int j = 0; j < 4; ++j) bf[j] = *(short8*)&Bs[(wn + j * 16 + lm) * BK + lk];
    #pragma unroll
    for (int i = 0; i < 4; ++i)
      #pragma unroll
      for (int j = 0; j < 4; ++j)
        acc[i][j] = __builtin_amdgcn_mfma_f32_16x16x32_bf16(af[i], bf[j], acc[i][j], 0, 0, 0);
    __syncthreads();
  }
  #undef LOADK

  #pragma unroll
  for (int i = 0; i < 4; ++i) {
    #pragma unroll
    for (int r = 0; r < 4; ++r) {
      float v = fmaxf(fmaxf(acc[i][0][r], acc[i][1][r]),
                      fmaxf(acc[i][2][r], acc[i][3][r]));
      v = fmaxf(v, __shfl_xor(v, 1, 64));
      v = fmaxf(v, __shfl_xor(v, 2, 64));
      v = fmaxf(v, __shfl_xor(v, 4, 64));
      v = fmaxf(v, __shfl_xor(v, 8, 64));
      if ((lane & 15) == 0) {
        int row = wm + i * 16 + (lane >> 4) * 4 + r;
        maxbuf[row][wave >> 1] = v;
      }
    }
  }
  __syncthreads();
  if (tid < BM) {
    float v = fmaxf(maxbuf[tid][0], maxbuf[tid][1]);
    unsigned e = __builtin_bit_cast(unsigned, v);
    e = ((int)e >= 0) ? (e | 0x80000000u) : ~e;
    atomicMax(&maxenc[(size_t)b * NQ + mt * BM + tid], e);
  }
}

// ============================================================================
extern "C" void kernel_launch(void* const* d_in, const int* in_sizes, int n_in,
                              void* d_out, int out_size, void* d_ws, size_t ws_size,
                              hipStream_t stream) {
  const float* q = (const float*)d_in[0];   // [8,2048,512]
  const float* s = (const float*)d_in[1];   // [8,4096,512]
  float* out = (float*)d_out;               // [8]

  unsigned* maxenc = (unsigned*)d_ws;                         // 64 KB
  const size_t QOFF = 65536;
  const size_t SOFF = QOFF + (size_t)NB * NQ * D;             // +8 MiB (fp8)
  const size_t NEED = SOFF + (size_t)NB * NS * D;             // +16 MiB (~25.2 MB total)

  if (ws_size >= NEED) {
    unsigned char* qn = (unsigned char*)d_ws + QOFF;
    unsigned char* sn = (unsigned char*)d_ws + SOFF;
    normcvt8_kernel<<<NB * (NQ + NS) / 4, 256, 0, stream>>>(q, s, qn, sn, maxenc);
    cosmax11_kernel<<<512, 256, 0, stream>>>(qn, sn, maxenc);   // 1-D, XCD-decoded
    finalize_kernel<<<NB, 256, 0, stream>>>(maxenc, out);
  } else {
    float* rq = (float*)((char*)d_ws + 65536);
    float* rs = (float*)((char*)d_ws + 131072);
    hipMemsetAsync(maxenc, 0, (size_t)NB * NQ * sizeof(unsigned), stream);
    norms_kernel<<<NB * (NQ + NS) / 4, 256, 0, stream>>>(q, s, rq, rs);
    dim3 grid(NS / BN, NQ / BM, NB);
    cosmax_kernel<<<grid, 256, 0, stream>>>(q, s, rq, rs, maxenc);
    finalize_kernel<<<NB, 256, 0, stream>>>(maxenc, out);
  }
}